// Round 7
// baseline (1042.232 us; speedup 1.0000x reference)
//
#include <hip/hip_runtime.h>
#include <math.h>

// Problem constants
#define BATCH 128
#define CIN   3
#define DIN   16
#define HWIN  64
#define COUT  24
#define DOUT  14   // 16 - 3 + 1
#define HOUT  62   // 64 - 3 + 1
#define WOUT  62
#define HW2   (HWIN * HWIN)
#define RS    68   // padded LDS row stride (floats); 16B-aligned, +2 overread ok

// x:    [128][3][16][64][64]  fp32
// w:    [24][3][3][3][3]      fp32  (co, cin, kd, kh, kw)
// bias: [24]
// out:  [128][24][62][62]     fp32 softmax over channel dim
//
// v7 = v6 with the tail prefetch bug fixed (v6 skipped the plane-14 prefetch
// at d=13, staging stale plane-13 data as plane 14 -> absmax 0.18).
// Structure: v2's proven thread layout (block = (b,ho) row; 192 thr = 24 co
// x 8 pixel strips; per-lane weights re-fetched through L1) + rolling depth
// accumulators with STATIC role rotation (depth unrolled by 3):
//   plane d feeds: birth slot X(d%3) with kd=0, X((d-1)%3) with kd=1,
//   X((d-2)%3) with kd=2 (then min+reset). Each plane LDS-read ONCE.
// No functions / array params (v3/v5 spilled to scratch that way).

__global__ __launch_bounds__(192, 3) void conv_min_softmax_v7(
    const float* __restrict__ x,
    const float* __restrict__ w,
    const float* __restrict__ bias,
    float* __restrict__ out)
{
    __shared__ __align__(16) float sx[9 * RS];   // one depth plane [cin*3+kh][col]
    __shared__ float sm[COUT][65];               // epilogue mins, 65 = conflict-free

    const int tid = threadIdx.x;
    const int bid = blockIdx.x;          // 0 .. 128*62-1
    const int ho  = bid % HOUT;
    const int b   = bid / HOUT;

    const int co = tid >> 3;             // 0..23  output channel
    const int wg = tid & 7;              // 0..7   pixel strip (wo = wg*8..wg*8+7)

    const float* xb  = x + (size_t)b * (CIN * DIN * HW2);
    const float* wco = w + co * 81;      // per-lane weights, L1-resident refetch

    // staging map: thread stores 3 elems/plane (one per cin) at row r, col wc
    const int r  = tid >> 6;             // 0..2
    const int wc = tid & 63;             // 0..63

    // global base offsets for the three cin rows this thread stages
    const int gb0 = (0 * DIN) * HW2 + (ho + r) * HWIN + wc;
    const int gb1 = (1 * DIN) * HW2 + (ho + r) * HWIN + wc;
    const int gb2 = (2 * DIN) * HW2 + (ho + r) * HWIN + wc;

    float X0[8], X1[8], X2[8], m[8];
    #pragma unroll
    for (int i = 0; i < 8; ++i) { X0[i] = 0.f; X1[i] = 0.f; X2[i] = 0.f; m[i] = 1e30f; }

    // software-pipelined staging registers
    float g0 = xb[gb0], g1 = xb[gb1], g2 = xb[gb2];
    float n0, n1, n2;
    int doff = HW2;                      // offset of plane d+1

    // ---- macros (no functions: keeps accumulators SROA-able) ----
#define STAGE(LAST)                                                        \
    sx[(0 * 3 + r) * RS + wc] = g0;                                        \
    sx[(1 * 3 + r) * RS + wc] = g1;                                        \
    sx[(2 * 3 + r) * RS + wc] = g2;                                        \
    if (!(LAST)) { n0 = xb[gb0 + doff]; n1 = xb[gb1 + doff]; n2 = xb[gb2 + doff]; } \
    __syncthreads();

#define ENDP()                                                             \
    __syncthreads();                                                       \
    g0 = n0; g1 = n1; g2 = n2; doff += HW2;

    // PLANE: SB gets kd=0 (birth), S1 gets kd=1, S2 gets kd=2.
    // DB/D1/D2 are compile-time 0/1 enables.
#define PLANE(SB, S1, S2, DB, D1, D2)                                      \
    {                                                                      \
        _Pragma("unroll")                                                  \
        for (int cin = 0; cin < 3; ++cin) {                                \
            _Pragma("unroll")                                              \
            for (int kh = 0; kh < 3; ++kh) {                               \
                const float* rp = sx + (cin * 3 + kh) * RS + wg * 8;       \
                float xr[10];                                              \
                {                                                          \
                    const float4 q0 = *(const float4*)(rp);                \
                    const float4 q1 = *(const float4*)(rp + 4);            \
                    const float2 q2 = *(const float2*)(rp + 8);            \
                    xr[0] = q0.x; xr[1] = q0.y; xr[2] = q0.z; xr[3] = q0.w;\
                    xr[4] = q1.x; xr[5] = q1.y; xr[6] = q1.z; xr[7] = q1.w;\
                    xr[8] = q2.x; xr[9] = q2.y;                            \
                }                                                          \
                _Pragma("unroll")                                          \
                for (int kw = 0; kw < 3; ++kw) {                           \
                    if (DB) {                                              \
                        const float wv = wco[cin * 27 + 0 * 9 + kh * 3 + kw]; \
                        _Pragma("unroll")                                  \
                        for (int i = 0; i < 8; ++i)                        \
                            SB[i] = fmaf(wv, xr[i + kw], SB[i]);           \
                    }                                                      \
                    if (D1) {                                              \
                        const float wv = wco[cin * 27 + 1 * 9 + kh * 3 + kw]; \
                        _Pragma("unroll")                                  \
                        for (int i = 0; i < 8; ++i)                        \
                            S1[i] = fmaf(wv, xr[i + kw], S1[i]);           \
                    }                                                      \
                    if (D2) {                                              \
                        const float wv = wco[cin * 27 + 2 * 9 + kh * 3 + kw]; \
                        _Pragma("unroll")                                  \
                        for (int i = 0; i < 8; ++i)                        \
                            S2[i] = fmaf(wv, xr[i + kw], S2[i]);           \
                    }                                                      \
                }                                                          \
            }                                                              \
        }                                                                  \
    }

#define MINRESET(S)                                                        \
    _Pragma("unroll")                                                      \
    for (int i = 0; i < 8; ++i) { m[i] = fminf(m[i], S[i]); S[i] = 0.f; }

    // ---- depth pipeline ----
    // d = 0: birth dz=0 in X0 (d%3 = 0)
    STAGE(0)
    PLANE(X0, X1, X2, 1, 0, 0)
    ENDP()

    // d = 1: birth dz=1 in X1; kd=1 for dz=0 (X0)
    STAGE(0)
    PLANE(X1, X0, X2, 1, 1, 0)
    ENDP()

    // d = 2..13: groups of 3, statically rotated roles.
    // All STAGE(0): even d=13 prefetches plane 14, which exists.
    #pragma unroll 1
    for (int d3 = 0; d3 < 4; ++d3) {
        // d = 3*d3+2: birth X2, kd1 X1, kd2 X0 -> min X0
        STAGE(0)
        PLANE(X2, X1, X0, 1, 1, 1)
        MINRESET(X0)
        ENDP()
        // d = 3*d3+3: birth X0, kd1 X2, kd2 X1 -> min X1
        STAGE(0)
        PLANE(X0, X2, X1, 1, 1, 1)
        MINRESET(X1)
        ENDP()
        // d = 3*d3+4: birth X1, kd1 X0, kd2 X2 -> min X2
        STAGE(0)
        PLANE(X1, X0, X2, 1, 1, 1)
        MINRESET(X2)
        ENDP()
    }

    // d = 14: kd1 for dz=13 (X1), kd2 for dz=12 (X0) -> min X0
    // STAGE(0) prefetches plane 15 (exists).
    STAGE(0)
    PLANE(X2, X1, X0, 0, 1, 1)
    MINRESET(X0)
    ENDP()

    // d = 15: kd2 for dz=13 (X1) -> min X1; nothing left to prefetch
    STAGE(1)
    PLANE(X2, X0, X1, 0, 0, 1)
    MINRESET(X1)

#undef STAGE
#undef ENDP
#undef PLANE
#undef MINRESET

    // ---- epilogue: bias, then per-pixel softmax across channels ----
    const float bco = bias[co];
    #pragma unroll
    for (int i = 0; i < 8; ++i) sm[co][wg * 8 + i] = m[i] + bco;  // cols 62..64 junk
    __syncthreads();

    if (tid < WOUT) {
        const int p = tid;
        float mx = -1e30f;
        #pragma unroll
        for (int c = 0; c < COUT; ++c) mx = fmaxf(mx, sm[c][p]);
        float e[COUT];
        float ssum = 0.f;
        #pragma unroll
        for (int c = 0; c < COUT; ++c) { e[c] = __expf(sm[c][p] - mx); ssum += e[c]; }
        const float inv = 1.f / ssum;
        float* ob = out + (size_t)b * COUT * (HOUT * WOUT) + ho * WOUT + p;
        #pragma unroll
        for (int c = 0; c < COUT; ++c) ob[(size_t)c * (HOUT * WOUT)] = e[c] * inv;
    }
}

extern "C" void kernel_launch(void* const* d_in, const int* in_sizes, int n_in,
                              void* d_out, int out_size, void* d_ws, size_t ws_size,
                              hipStream_t stream) {
    const float* x    = (const float*)d_in[0];
    const float* w    = (const float*)d_in[1];
    const float* bias = (const float*)d_in[2];
    float* out = (float*)d_out;

    const int blocks = BATCH * HOUT;     // 7936
    conv_min_softmax_v7<<<blocks, 192, 0, stream>>>(x, w, bias, out);
}